// Round 1
// baseline (199.250 us; speedup 1.0000x reference)
//
#include <hip/hip_runtime.h>
#include <math.h>

// Problem constants (reference: SNR_DB=20 -> noise_power = signal_power/100)
#define L_TOTAL (1 << 24)

constexpr float A_COEF = 0.98f;   // 1 - B
constexpr float B_COEF = 0.02f;

constexpr int T  = 256;           // threads / block
constexpr int S  = 16;            // elements / thread / tile
constexpr int TS = T * S;         // 4096 tile
constexpr int K_OUT = 4;          // output tiles per block (+1 warm-up tile)
// blocks = L / (K_OUT*TS) = 16777216 / 16384 = 1024

// ---------------------------------------------------------------------------
// Kernel 1: sum of squares of audio -> double accumulator in workspace
// ---------------------------------------------------------------------------
__global__ __launch_bounds__(256) void sumsq_kernel(const float4* __restrict__ a4,
                                                    double* __restrict__ acc,
                                                    int n4) {
    int idx    = blockIdx.x * blockDim.x + threadIdx.x;
    int stride = gridDim.x * blockDim.x;
    float s = 0.f;
    for (int i = idx; i < n4; i += stride) {
        float4 v = a4[i];
        s += v.x * v.x + v.y * v.y + v.z * v.z + v.w * v.w;
    }
    // wave (64-lane) reduction
    #pragma unroll
    for (int o = 32; o > 0; o >>= 1) s += __shfl_down(s, o, 64);
    __shared__ float wsum[4];
    int lane = threadIdx.x & 63;
    int wv   = threadIdx.x >> 6;
    if (lane == 0) wsum[wv] = s;
    __syncthreads();
    if (threadIdx.x == 0) {
        float b = wsum[0] + wsum[1] + wsum[2] + wsum[3];
        atomicAdd(acc, (double)b);
    }
}

// ---------------------------------------------------------------------------
// Kernel 2: pink-noise scan + scale + add, block-parallel with warm-up tile.
//
// Recurrence p[i] = A*p[i-1] + B*w[i], p[0] = 0 (u[0] forced to 0).
// 0.98^4096 ~ 1e-36 => one 4096-sample warm-up tile reconstructs the carry
// exactly to fp32 precision; blocks are fully independent.
// ---------------------------------------------------------------------------
__global__ __launch_bounds__(256) void pink_add_kernel(const float* __restrict__ audio,
                                                       const float* __restrict__ white,
                                                       const double* __restrict__ acc,
                                                       float* __restrict__ out) {
    // scale = sqrt(mean(audio^2) / 100)
    const float scale = (float)sqrt((*acc) * (1.0 / ((double)L_TOTAL * 100.0)));

    __shared__ float lds[TS + TS / 16];   // padded p-values (17 floats per 16)
    __shared__ float wave_tot[4];

    const int tid  = threadIdx.x;
    const int lane = tid & 63;
    const int wv   = tid >> 6;
    const int block_start = blockIdx.x * (K_OUT * TS);

    // beta = A^S and its powers (float squaring chain; precision irrelevant
    // at our tolerance since these only scale tiny carry corrections)
    const float a2 = A_COEF * A_COEF;
    const float a4 = a2 * a2;
    const float a8 = a4 * a4;
    const float beta = a8 * a8;            // 0.98^16
    const float b2 = beta * beta, b4 = b2 * b2, b8 = b4 * b4;
    const float b16 = b8 * b8, b32 = b16 * b16, b64 = b32 * b32;
    const float bpow[6] = {beta, b2, b4, b8, b16, b32};

    // beta^lane and beta^tid (for carry-in propagation)
    const float beta_l = exp2f((float)lane * log2f(beta));
    float b64w = 1.f;
    #pragma unroll
    for (int i = 0; i < 3; ++i) if (wv > i) b64w *= b64;
    const float beta_t = beta_l * b64w;    // beta^tid
    const float b256 = b64 * b64 * b64 * b64;  // ~1e-36 (dead, kept for exactness)

    float c_tile = 0.f;   // p value at the end of the previous tile

    for (int k = -1; k < K_OUT; ++k) {
        const int base = block_start + k * TS;
        const int g0   = base + tid * S;

        // ---- load 16 whites (float4 x4), mask OOB (block 0 warm-up) ----
        float w[S];
        if (g0 >= 0) {
            const float4* wp = reinterpret_cast<const float4*>(white + g0);
            #pragma unroll
            for (int q = 0; q < S / 4; ++q) {
                float4 v = wp[q];
                w[4 * q + 0] = v.x; w[4 * q + 1] = v.y;
                w[4 * q + 2] = v.z; w[4 * q + 3] = v.w;
            }
        } else {
            #pragma unroll
            for (int j = 0; j < S; ++j) w[j] = 0.f;
        }
        // u[i] = B*w[i], with u[0] = 0 globally (reference .at[0].set(0))
        #pragma unroll
        for (int j = 0; j < S; ++j) w[j] = (g0 + j > 0) ? B_COEF * w[j] : 0.f;

        // ---- pass 1: local scan with zero init -> segment aggregate U ----
        float p = 0.f;
        #pragma unroll
        for (int j = 0; j < S; ++j) p = fmaf(A_COEF, p, w[j]);

        // ---- wave inclusive scan of (beta, U) pairs (constant A) ----
        float W = p;
        #pragma unroll
        for (int i = 0; i < 6; ++i) {
            const int o = 1 << i;
            float up = __shfl_up(W, o, 64);
            if (lane >= o) W = fmaf(bpow[i], up, W);
        }
        if (lane == 63) wave_tot[wv] = W;
        __syncthreads();   // B1: wave totals visible

        // ---- cross-wave prefixes ----
        const float G0 = wave_tot[0], G1 = wave_tot[1];
        const float G2 = wave_tot[2], G3 = wave_tot[3];
        const float P1 = G0;
        const float P2 = fmaf(P1, b64, G1);
        const float P3 = fmaf(P2, b64, G2);
        const float P  = (wv == 0) ? 0.f : (wv == 1) ? P1 : (wv == 2) ? P2 : P3;
        const float c_next = fmaf(P3, b64, G3) + c_tile * b256;

        // exclusive carry for this thread (x at end of segment tid-1)
        const float Wp = __shfl_up(W, 1, 64);
        const float E  = ((lane == 0) ? 0.f : Wp) + P * beta_l;
        const float C  = E + c_tile * beta_t;
        c_tile = c_next;

        if (k >= 0) {
            // ---- pass 2: exact scan with carry-in, write padded LDS ----
            float p2 = C;
            const int lb = tid * 17;   // (tid*16 + j) + ((tid*16+j)>>4) = 17*tid + j
            #pragma unroll
            for (int j = 0; j < S; ++j) {
                p2 = fmaf(A_COEF, p2, w[j]);
                lds[lb + j] = p2;
            }
            __syncthreads();   // B2: p values visible

            // ---- output: coalesced float4 audio read + fused store ----
            const float4* ap = reinterpret_cast<const float4*>(audio + base);
            float4*       op = reinterpret_cast<float4*>(out + base);
            #pragma unroll
            for (int q = 0; q < 4; ++q) {
                const int i4 = q * T + tid;   // float4 index within tile
                const int i  = i4 * 4;
                const int pi = i + (i >> 4);  // i..i+3 share the pad offset
                float4 a = ap[i4];
                float4 r;
                r.x = fmaf(lds[pi + 0], scale, a.x);
                r.y = fmaf(lds[pi + 1], scale, a.y);
                r.z = fmaf(lds[pi + 2], scale, a.z);
                r.w = fmaf(lds[pi + 3], scale, a.w);
                op[i4] = r;
            }
        }
        __syncthreads();   // B3: protect wave_tot/lds before next tile
    }
}

// ---------------------------------------------------------------------------
extern "C" void kernel_launch(void* const* d_in, const int* in_sizes, int n_in,
                              void* d_out, int out_size, void* d_ws, size_t ws_size,
                              hipStream_t stream) {
    const float* audio = (const float*)d_in[0];
    const float* white = (const float*)d_in[1];
    float* out         = (float*)d_out;
    double* acc        = (double*)d_ws;

    // zero the accumulator (ws is poisoned 0xAA before every launch)
    hipMemsetAsync(d_ws, 0, sizeof(double), stream);

    const int n4 = L_TOTAL / 4;
    sumsq_kernel<<<2048, 256, 0, stream>>>((const float4*)audio, acc, n4);

    const int blocks = L_TOTAL / (K_OUT * TS);   // 1024
    pink_add_kernel<<<blocks, 256, 0, stream>>>(audio, white, acc, out);
}

// Round 2
// 179.823 us; speedup vs baseline: 1.1080x; 1.1080x over previous
//
#include <hip/hip_runtime.h>
#include <math.h>

// Problem constants (reference: SNR_DB=20 -> noise_power = signal_power/100)
#define L_TOTAL (1 << 24)

constexpr float A_COEF = 0.98f;   // 1 - B
constexpr float B_COEF = 0.02f;

constexpr int T    = 256;         // threads / block
constexpr int S    = 16;          // elements / thread
constexpr int TS   = T * S;       // 4096 samples / block
constexpr int WARM = 512;         // warm-up samples (0.98^512 ~ 3e-5 -> err ~1e-6)
// grid = L / TS = 4096 blocks

// ---------------------------------------------------------------------------
// Kernel 1: sum of squares of audio -> double accumulator in workspace.
// Also warms L3 with the audio array for the pink kernel's re-read.
// ---------------------------------------------------------------------------
__global__ __launch_bounds__(256) void sumsq_kernel(const float4* __restrict__ a4,
                                                    double* __restrict__ acc,
                                                    int n4) {
    int idx    = blockIdx.x * blockDim.x + threadIdx.x;
    int stride = gridDim.x * blockDim.x;
    float s = 0.f;
    for (int i = idx; i < n4; i += stride) {
        float4 v = a4[i];
        s += v.x * v.x + v.y * v.y + v.z * v.z + v.w * v.w;
    }
    #pragma unroll
    for (int o = 32; o > 0; o >>= 1) s += __shfl_down(s, o, 64);
    __shared__ float wsum[4];
    int lane = threadIdx.x & 63;
    int wv   = threadIdx.x >> 6;
    if (lane == 0) wsum[wv] = s;
    __syncthreads();
    if (threadIdx.x == 0) {
        float b = wsum[0] + wsum[1] + wsum[2] + wsum[3];
        atomicAdd(acc, (double)b);
    }
}

// ---------------------------------------------------------------------------
// Kernel 2: one 4096-sample tile per block, single pass.
//
// p[i] = A*p[i-1] + B*w[i], p[0]=0. Blocks are independent: the carry into a
// block is reconstructed from a 512-sample warm-up window, computed as a
// weighted REDUCTION (u_i * A^{511-i}) in parallel with the main tile scan,
// then injected through the linear-recurrence identity
//   carry(thread tid) = E_tid + Cw * A^(16*tid).
// All global loads (audio, white, warm-up) are issued before any compute;
// only 2 barriers per block.
// ---------------------------------------------------------------------------
__global__ __launch_bounds__(256) void pink_add_kernel(const float* __restrict__ audio,
                                                       const float* __restrict__ white,
                                                       const double* __restrict__ acc,
                                                       float* __restrict__ out) {
    const float scale = (float)sqrt((*acc) * (1.0 / ((double)L_TOTAL * 100.0)));

    __shared__ float lds[TS + TS / 16];   // padded p-values (17 floats per 16)
    __shared__ float wave_tot[4];
    __shared__ float wsum[4];

    const int tid  = threadIdx.x;
    const int lane = tid & 63;
    const int wv   = tid >> 6;
    const int base = blockIdx.x * TS;

    // ---- issue ALL global loads up front (latency overlap) ----
    // audio, in the coalesced layout the output phase uses
    const float4* ap = reinterpret_cast<const float4*>(audio + base);
    float4 av[4];
    #pragma unroll
    for (int q = 0; q < 4; ++q) av[q] = ap[q * T + tid];

    // main whites: 16 contiguous per thread
    const float4* wp = reinterpret_cast<const float4*>(white + base + tid * S);
    float w[S];
    #pragma unroll
    for (int q = 0; q < S / 4; ++q) {
        float4 v = wp[q];
        w[4 * q + 0] = v.x; w[4 * q + 1] = v.y;
        w[4 * q + 2] = v.z; w[4 * q + 3] = v.w;
    }

    // warm-up whites: 2 per thread from [base-512, base)
    float2 wu = make_float2(0.f, 0.f);
    if (blockIdx.x > 0) {
        const float2* up = reinterpret_cast<const float2*>(white + base - WARM);
        wu = up[tid];
    }

    // ---- constants: beta = A^16 and powers ----
    const float a2 = A_COEF * A_COEF;
    const float a4 = a2 * a2;
    const float a8 = a4 * a4;
    const float beta = a8 * a8;                           // A^16
    const float b2 = beta * beta, b4 = b2 * b2, b8 = b4 * b4;
    const float b16 = b8 * b8, b32 = b16 * b16, b64 = b32 * b32;
    const float bpow[6] = {beta, b2, b4, b8, b16, b32};

    const float beta_l = exp2f((float)lane * log2f(beta)); // beta^lane
    float b64w = 1.f;
    #pragma unroll
    for (int i = 0; i < 3; ++i) if (wv > i) b64w *= b64;
    const float beta_t = beta_l * b64w;                    // A^(16*tid)

    // ---- u transform (u = B*w, u[0]=0 globally) ----
    #pragma unroll
    for (int j = 0; j < S; ++j) w[j] *= B_COEF;
    if (base == 0 && tid == 0) w[0] = 0.f;

    // ---- local zero-init scan -> segment aggregate ----
    float p = 0.f;
    #pragma unroll
    for (int j = 0; j < S; ++j) p = fmaf(A_COEF, p, w[j]);

    // ---- wave inclusive scan of segment aggregates ----
    float W = p;
    #pragma unroll
    for (int i = 0; i < 6; ++i) {
        const int o = 1 << i;
        float up = __shfl_up(W, o, 64);
        if (lane >= o) W = fmaf(bpow[i], up, W);
    }

    // ---- warm-up carry: weighted reduction, in parallel with scan ----
    // thread tid owns warm-up positions 2*tid, 2*tid+1 (of 512);
    // contribution to p at end of warm-up: (A*u0 + u1) * (A^2)^(255-tid)
    float part = fmaf(A_COEF, B_COEF * wu.x, B_COEF * wu.y);
    part *= exp2f((float)(255 - tid) * log2f(a2));
    #pragma unroll
    for (int o = 32; o > 0; o >>= 1) part += __shfl_down(part, o, 64);

    if (lane == 63) wave_tot[wv] = W;
    if (lane == 0)  wsum[wv] = part;
    __syncthreads();   // B1

    // ---- cross-wave prefixes + warm-up carry ----
    const float G0 = wave_tot[0], G1 = wave_tot[1];
    const float G2 = wave_tot[2], G3 = wave_tot[3];
    const float P1 = G0;
    const float P2 = fmaf(P1, b64, G1);
    const float P3 = fmaf(P2, b64, G2);
    const float P  = (wv == 0) ? 0.f : (wv == 1) ? P1 : (wv == 2) ? P2 : P3;
    const float Cw = wsum[0] + wsum[1] + wsum[2] + wsum[3];   // p at end of warm-up

    const float Wp = __shfl_up(W, 1, 64);
    const float E  = ((lane == 0) ? 0.f : Wp) + P * beta_l;   // zero-init excl. prefix
    const float C  = E + Cw * beta_t;                         // + warm-up carry

    // ---- pass 2: exact scan with carry-in, write padded LDS ----
    float p2 = C;
    const int lb = tid * 17;
    #pragma unroll
    for (int j = 0; j < S; ++j) {
        p2 = fmaf(A_COEF, p2, w[j]);
        lds[lb + j] = p2;
    }
    __syncthreads();   // B2

    // ---- output: audio already in registers, coalesced float4 store ----
    float4* op = reinterpret_cast<float4*>(out + base);
    #pragma unroll
    for (int q = 0; q < 4; ++q) {
        const int i4 = q * T + tid;
        const int i  = i4 * 4;
        const int pi = i + (i >> 4);
        float4 a = av[q];
        float4 r;
        r.x = fmaf(lds[pi + 0], scale, a.x);
        r.y = fmaf(lds[pi + 1], scale, a.y);
        r.z = fmaf(lds[pi + 2], scale, a.z);
        r.w = fmaf(lds[pi + 3], scale, a.w);
        op[i4] = r;
    }
}

// ---------------------------------------------------------------------------
extern "C" void kernel_launch(void* const* d_in, const int* in_sizes, int n_in,
                              void* d_out, int out_size, void* d_ws, size_t ws_size,
                              hipStream_t stream) {
    const float* audio = (const float*)d_in[0];
    const float* white = (const float*)d_in[1];
    float* out         = (float*)d_out;
    double* acc        = (double*)d_ws;

    hipMemsetAsync(d_ws, 0, sizeof(double), stream);

    const int n4 = L_TOTAL / 4;
    sumsq_kernel<<<1024, 256, 0, stream>>>((const float4*)audio, acc, n4);

    const int blocks = L_TOTAL / TS;   // 4096
    pink_add_kernel<<<blocks, 256, 0, stream>>>(audio, white, acc, out);
}

// Round 3
// 171.416 us; speedup vs baseline: 1.1624x; 1.0490x over previous
//
#include <hip/hip_runtime.h>
#include <math.h>

// Problem constants (reference: SNR_DB=20 -> noise_power = signal_power/100)
#define L_TOTAL (1 << 24)

constexpr float A_COEF = 0.98f;   // 1 - B
constexpr float B_COEF = 0.02f;

constexpr int T    = 256;         // threads / block
constexpr int S    = 16;          // elements / thread
constexpr int TS   = T * S;       // 4096 samples / block
constexpr int WARM = 512;         // warm-up samples (0.98^512 ~ 3e-5 -> err ~1e-6)
constexpr int NPART = 1024;       // sumsq partials

// LDS-only barrier: does NOT drain vmcnt, so global loads stay in flight
// across it (plain __syncthreads compiles to s_waitcnt vmcnt(0) lgkmcnt(0)
// + s_barrier, which convoys every resident block on the VMEM queue).
// Safe here because only LDS data crosses the barrier.
__device__ __forceinline__ void block_sync_lds() {
    asm volatile("s_waitcnt lgkmcnt(0)\n\ts_barrier" ::: "memory");
}

// ---------------------------------------------------------------------------
// Kernel 1: per-block partial sums of audio^2 -> d_ws[0..1023] (no atomics,
// no memset needed; also pre-warms L3 with audio for the pink kernel).
// ---------------------------------------------------------------------------
__global__ __launch_bounds__(256) void sumsq_kernel(const float4* __restrict__ a4,
                                                    float* __restrict__ partials,
                                                    int n4) {
    int idx    = blockIdx.x * blockDim.x + threadIdx.x;
    int stride = gridDim.x * blockDim.x;
    float s = 0.f;
    for (int i = idx; i < n4; i += stride) {
        float4 v = a4[i];
        s += v.x * v.x + v.y * v.y + v.z * v.z + v.w * v.w;
    }
    #pragma unroll
    for (int o = 32; o > 0; o >>= 1) s += __shfl_down(s, o, 64);
    __shared__ float wsum[4];
    int lane = threadIdx.x & 63;
    int wv   = threadIdx.x >> 6;
    if (lane == 0) wsum[wv] = s;
    __syncthreads();
    if (threadIdx.x == 0)
        partials[blockIdx.x] = wsum[0] + wsum[1] + wsum[2] + wsum[3];
}

// ---------------------------------------------------------------------------
// Kernel 2: one 4096-sample tile per block, single pass, 2 LDS-only barriers.
// p[i] = A*p[i-1] + B*w[i], p[0]=0. Carry into a block is reconstructed from
// a 512-sample warm-up window (weighted reduction, fused with the scan phase).
// Pass 2 is de-serialized: p[j] = local_scan[j] + C * A^(j+1).
// ---------------------------------------------------------------------------
__global__ __launch_bounds__(256) void pink_add_kernel(const float* __restrict__ audio,
                                                       const float* __restrict__ white,
                                                       const float* __restrict__ partials,
                                                       float* __restrict__ out) {
    __shared__ float lds[TS + TS / 16];   // padded p-values (17 floats per 16)
    __shared__ float wave_tot[4];
    __shared__ float wsum[4];
    __shared__ float psum[4];

    const int tid  = threadIdx.x;
    const int lane = tid & 63;
    const int wv   = tid >> 6;
    const int base = blockIdx.x * TS;

    // ---- issue scan-gating loads FIRST (white, warm-up, partials) ----
    const float4* wp = reinterpret_cast<const float4*>(white + base + tid * S);
    float w[S];
    #pragma unroll
    for (int q = 0; q < S / 4; ++q) {
        float4 v = wp[q];
        w[4 * q + 0] = v.x; w[4 * q + 1] = v.y;
        w[4 * q + 2] = v.z; w[4 * q + 3] = v.w;
    }
    float2 wu = make_float2(0.f, 0.f);
    if (blockIdx.x > 0) {
        const float2* up = reinterpret_cast<const float2*>(white + base - WARM);
        wu = up[tid];
    }
    const float4 pp = reinterpret_cast<const float4*>(partials)[tid];  // 256*4 = 1024

    // ---- constants ----
    float apow[S];                         // A^(j+1), j=0..15
    apow[0] = A_COEF;
    #pragma unroll
    for (int j = 1; j < S; ++j) apow[j] = apow[j - 1] * A_COEF;
    const float beta = apow[S - 1];        // A^16
    const float b2 = beta * beta, b4 = b2 * b2, b8 = b4 * b4;
    const float b16 = b8 * b8, b32 = b16 * b16, b64 = b32 * b32;
    const float bpow[6] = {beta, b2, b4, b8, b16, b32};

    const float beta_l = exp2f((float)lane * log2f(beta));   // beta^lane
    float b64w = 1.f;
    #pragma unroll
    for (int i = 0; i < 3; ++i) if (wv > i) b64w *= b64;
    const float beta_t = beta_l * b64w;                      // A^(16*tid)

    // ---- u transform (u = B*w, u[0]=0 globally) ----
    #pragma unroll
    for (int j = 0; j < S; ++j) w[j] *= B_COEF;
    if (base == 0 && tid == 0) w[0] = 0.f;

    // ---- pass 1: local zero-init scan, keep all locals ----
    float l[S];
    float p = 0.f;
    #pragma unroll
    for (int j = 0; j < S; ++j) { p = fmaf(A_COEF, p, w[j]); l[j] = p; }

    // ---- wave inclusive scan of segment aggregates ----
    float W = p;
    #pragma unroll
    for (int i = 0; i < 6; ++i) {
        const int o = 1 << i;
        float up = __shfl_up(W, o, 64);
        if (lane >= o) W = fmaf(bpow[i], up, W);
    }

    // ---- warm-up carry: weighted reduction (parallel with scan) ----
    const float a2c = A_COEF * A_COEF;
    float part = fmaf(A_COEF, B_COEF * wu.x, B_COEF * wu.y);
    part *= exp2f((float)(255 - tid) * log2f(a2c));
    #pragma unroll
    for (int o = 32; o > 0; o >>= 1) part += __shfl_down(part, o, 64);

    // ---- sumsq partial reduction (parallel with scan) ----
    float ss = pp.x + pp.y + pp.z + pp.w;
    #pragma unroll
    for (int o = 32; o > 0; o >>= 1) ss += __shfl_down(ss, o, 64);

    if (lane == 63) wave_tot[wv] = W;
    if (lane == 0)  { wsum[wv] = part; psum[wv] = ss; }
    block_sync_lds();   // B1 (LDS-only: vmem stays in flight)

    // ---- cross-wave prefixes + warm-up carry + scale ----
    const float G0 = wave_tot[0], G1 = wave_tot[1];
    const float G2 = wave_tot[2], G3 = wave_tot[3];
    const float P1 = G0;
    const float P2 = fmaf(P1, b64, G1);
    const float P3 = fmaf(P2, b64, G2);
    const float P  = (wv == 0) ? 0.f : (wv == 1) ? P1 : (wv == 2) ? P2 : P3;
    const float Cw = wsum[0] + wsum[1] + wsum[2] + wsum[3];   // p at end of warm-up
    const float sumsq = psum[0] + psum[1] + psum[2] + psum[3];
    const float scale = sqrtf(sumsq * (1.0f / ((float)L_TOTAL * 100.0f)));

    const float Wp = __shfl_up(W, 1, 64);
    const float E  = ((lane == 0) ? 0.f : Wp) + P * beta_l;   // zero-init excl. prefix
    const float C  = E + Cw * beta_t;                         // + warm-up carry

    // ---- pass 2: INDEPENDENT fmas, write padded LDS ----
    const int lb = tid * 17;
    #pragma unroll
    for (int j = 0; j < S; ++j)
        lds[lb + j] = fmaf(C, apow[j], l[j]);

    // ---- audio loads issued here: latency hides inside the barrier ----
    const float4* ap = reinterpret_cast<const float4*>(audio + base);
    float4 av[4];
    #pragma unroll
    for (int q = 0; q < 4; ++q) av[q] = ap[q * T + tid];

    block_sync_lds();   // B2 (LDS-only)

    // ---- output: coalesced float4 store ----
    float4* op = reinterpret_cast<float4*>(out + base);
    #pragma unroll
    for (int q = 0; q < 4; ++q) {
        const int i4 = q * T + tid;
        const int i  = i4 * 4;
        const int pi = i + (i >> 4);
        float4 a = av[q];
        float4 r;
        r.x = fmaf(lds[pi + 0], scale, a.x);
        r.y = fmaf(lds[pi + 1], scale, a.y);
        r.z = fmaf(lds[pi + 2], scale, a.z);
        r.w = fmaf(lds[pi + 3], scale, a.w);
        op[i4] = r;
    }
}

// ---------------------------------------------------------------------------
extern "C" void kernel_launch(void* const* d_in, const int* in_sizes, int n_in,
                              void* d_out, int out_size, void* d_ws, size_t ws_size,
                              hipStream_t stream) {
    const float* audio = (const float*)d_in[0];
    const float* white = (const float*)d_in[1];
    float* out         = (float*)d_out;
    float* partials    = (float*)d_ws;   // 1024 floats, fully overwritten by sumsq

    const int n4 = L_TOTAL / 4;
    sumsq_kernel<<<NPART, 256, 0, stream>>>((const float4*)audio, partials, n4);

    const int blocks = L_TOTAL / TS;   // 4096
    pink_add_kernel<<<blocks, 256, 0, stream>>>(audio, white, partials, out);
}

// Round 4
// 170.246 us; speedup vs baseline: 1.1704x; 1.0069x over previous
//
#include <hip/hip_runtime.h>
#include <math.h>

// Problem constants (reference: SNR_DB=20 -> noise_power = signal_power/100)
#define L_TOTAL (1 << 24)

constexpr float A_COEF = 0.98f;   // 1 - B
constexpr float B_COEF = 0.02f;

constexpr int T    = 256;         // threads / block
constexpr int TS   = 4096;        // samples / block (4 float4 groups x 256 threads)
constexpr int WARM = 512;         // warm-up samples (0.98^512 ~ 3e-5 -> err ~1e-6)
constexpr int NPART = 1024;       // sumsq partials

// LDS-only barrier: does NOT drain vmcnt (global loads stay in flight).
__device__ __forceinline__ void block_sync_lds() {
    asm volatile("s_waitcnt lgkmcnt(0)\n\ts_barrier" ::: "memory");
}

// ---------------------------------------------------------------------------
// Kernel 1: per-block partial sums of audio^2 -> d_ws[0..1023]
// (also pre-warms L3 with audio for the pink kernel's re-read)
// ---------------------------------------------------------------------------
__global__ __launch_bounds__(256) void sumsq_kernel(const float4* __restrict__ a4,
                                                    float* __restrict__ partials,
                                                    int n4) {
    int idx    = blockIdx.x * blockDim.x + threadIdx.x;
    int stride = gridDim.x * blockDim.x;
    float s = 0.f;
    for (int i = idx; i < n4; i += stride) {
        float4 v = a4[i];
        s += v.x * v.x + v.y * v.y + v.z * v.z + v.w * v.w;
    }
    #pragma unroll
    for (int o = 32; o > 0; o >>= 1) s += __shfl_down(s, o, 64);
    __shared__ float wsum[4];
    int lane = threadIdx.x & 63;
    int wv   = threadIdx.x >> 6;
    if (lane == 0) wsum[wv] = s;
    __syncthreads();
    if (threadIdx.x == 0)
        partials[blockIdx.x] = wsum[0] + wsum[1] + wsum[2] + wsum[3];
}

// ---------------------------------------------------------------------------
// Kernel 2: one 4096-sample tile per block. ALL global accesses (white, audio,
// store) are lane-contiguous float4 — thread t owns elements 1024q + 4t..+3
// for q=0..3, i.e. 4 runs of 4. Four independent 256-wide scans (multiplier
// A^4 per segment) + cross-group carry chain (factor A^1024). Output p-values
// are produced directly in store layout: no LDS transpose at all.
// ---------------------------------------------------------------------------
__global__ __launch_bounds__(256) void pink_add_kernel(const float* __restrict__ audio,
                                                       const float* __restrict__ white,
                                                       const float* __restrict__ partials,
                                                       float* __restrict__ out) {
    __shared__ float gtot[4][4];   // [group q][wave] inclusive wave totals
    __shared__ float wsum[4];      // warm-up partials per wave
    __shared__ float psum[4];      // sumsq partials per wave

    const int tid  = threadIdx.x;
    const int lane = tid & 63;
    const int wv   = tid >> 6;
    const int base = blockIdx.x * TS;

    // ---- issue ALL global loads up front, all perfectly coalesced ----
    const float4* wp4 = reinterpret_cast<const float4*>(white + base);
    float4 u[4];
    #pragma unroll
    for (int q = 0; q < 4; ++q) u[q] = wp4[q * T + tid];

    float2 wu = make_float2(0.f, 0.f);
    if (blockIdx.x > 0) {
        const float2* up = reinterpret_cast<const float2*>(white + base - WARM);
        wu = up[tid];
    }
    const float4 pp = reinterpret_cast<const float4*>(partials)[tid];  // 256*4 = 1024

    const float4* ap4 = reinterpret_cast<const float4*>(audio + base);
    float4 av[4];
    #pragma unroll
    for (int q = 0; q < 4; ++q) av[q] = ap4[q * T + tid];

    // ---- constants ----
    const float a2c  = A_COEF * A_COEF;
    const float b4c  = a2c * a2c;                    // A^4  (segment multiplier)
    const float b8c  = b4c * b4c, b16c = b8c * b8c, b32c = b16c * b16c;
    const float b64c = b32c * b32c, b128c = b64c * b64c;
    const float b256c  = b128c * b128c;              // A^256  (wave factor)
    const float b1024c = b256c * b256c * b256c * b256c;  // A^1024 (group factor)
    const float bpow[6] = {b4c, b8c, b16c, b32c, b64c, b128c};
    const float cg[4] = {1.f, b1024c, b1024c * b1024c, b1024c * b1024c * b1024c};

    const float b4lane = exp2f((float)lane * log2f(b4c));   // A^(4*lane)
    float b256w = 1.f;
    #pragma unroll
    for (int i = 0; i < 3; ++i) if (wv > i) b256w *= b256c;
    const float b4t = b4lane * b256w;                       // A^(4*tid)

    // ---- u = B*w, u[0] = 0 globally ----
    #pragma unroll
    for (int q = 0; q < 4; ++q) {
        u[q].x *= B_COEF; u[q].y *= B_COEF; u[q].z *= B_COEF; u[q].w *= B_COEF;
    }
    if (base == 0 && tid == 0) u[0].x = 0.f;

    // ---- local zero-init scans (4 elements each) -> segment aggregates ----
    float W[4];
    #pragma unroll
    for (int q = 0; q < 4; ++q) {
        float p = u[q].x;
        p = fmaf(A_COEF, p, u[q].y);
        p = fmaf(A_COEF, p, u[q].z);
        p = fmaf(A_COEF, p, u[q].w);
        W[q] = p;
    }

    // ---- 4 independent wave scans (interleaved for ILP) ----
    #pragma unroll
    for (int i = 0; i < 6; ++i) {
        const int o = 1 << i;
        #pragma unroll
        for (int q = 0; q < 4; ++q) {
            float up = __shfl_up(W[q], o, 64);
            if (lane >= o) W[q] = fmaf(bpow[i], up, W[q]);
        }
    }

    // ---- warm-up carry: weighted reduction ----
    float part = fmaf(A_COEF, B_COEF * wu.x, B_COEF * wu.y);
    part *= exp2f((float)(255 - tid) * log2f(a2c));
    #pragma unroll
    for (int o = 32; o > 0; o >>= 1) part += __shfl_down(part, o, 64);

    // ---- sumsq partial reduction ----
    float ss = pp.x + pp.y + pp.z + pp.w;
    #pragma unroll
    for (int o = 32; o > 0; o >>= 1) ss += __shfl_down(ss, o, 64);

    if (lane == 63) {
        #pragma unroll
        for (int q = 0; q < 4; ++q) gtot[q][wv] = W[q];
    }
    if (lane == 0) { wsum[wv] = part; psum[wv] = ss; }
    block_sync_lds();   // only barrier in the kernel (LDS-only)

    // ---- cross-wave prefixes per group + group totals ----
    float P[4], Gt[4];
    #pragma unroll
    for (int q = 0; q < 4; ++q) {
        const float G0 = gtot[q][0], G1 = gtot[q][1];
        const float G2 = gtot[q][2], G3 = gtot[q][3];
        const float P1 = G0;
        const float P2 = fmaf(P1, b256c, G1);
        const float P3 = fmaf(P2, b256c, G2);
        P[q]  = (wv == 0) ? 0.f : (wv == 1) ? P1 : (wv == 2) ? P2 : P3;
        Gt[q] = fmaf(P3, b256c, G3);
    }
    const float Cw    = wsum[0] + wsum[1] + wsum[2] + wsum[3];
    const float sumsq = psum[0] + psum[1] + psum[2] + psum[3];
    const float scale = sqrtf(sumsq * (1.0f / ((float)L_TOTAL * 100.0f)));

    // ---- cross-group carry chain (zero-init at block start) ----
    float H[4];
    H[0] = 0.f;
    H[1] = Gt[0];
    H[2] = fmaf(H[1], b1024c, Gt[1]);
    H[3] = fmaf(H[2], b1024c, Gt[2]);

    // ---- per-thread carries, final p recompute, fused output ----
    float4* op4 = reinterpret_cast<float4*>(out + base);
    #pragma unroll
    for (int q = 0; q < 4; ++q) {
        const float Wp = __shfl_up(W[q], 1, 64);
        const float E  = ((lane == 0) ? 0.f : Wp) + P[q] * b4lane;
        const float C  = E + fmaf(Cw, cg[q], H[q] / 1.0f) * b4t
                           - H[q] * b4t + (H[q] + Cw * cg[q]) * b4t;  // simplified below
        // (kept simple & exact:)
        const float Cx = E + (H[q] + Cw * cg[q]) * b4t;

        float p = Cx;
        float4 r;
        p = fmaf(A_COEF, p, u[q].x); r.x = fmaf(p, scale, av[q].x);
        p = fmaf(A_COEF, p, u[q].y); r.y = fmaf(p, scale, av[q].y);
        p = fmaf(A_COEF, p, u[q].z); r.z = fmaf(p, scale, av[q].z);
        p = fmaf(A_COEF, p, u[q].w); r.w = fmaf(p, scale, av[q].w);
        (void)C;
        op4[q * T + tid] = r;
    }
}

// ---------------------------------------------------------------------------
extern "C" void kernel_launch(void* const* d_in, const int* in_sizes, int n_in,
                              void* d_out, int out_size, void* d_ws, size_t ws_size,
                              hipStream_t stream) {
    const float* audio = (const float*)d_in[0];
    const float* white = (const float*)d_in[1];
    float* out         = (float*)d_out;
    float* partials    = (float*)d_ws;   // 1024 floats, fully overwritten by sumsq

    const int n4 = L_TOTAL / 4;
    sumsq_kernel<<<NPART, 256, 0, stream>>>((const float4*)audio, partials, n4);

    const int blocks = L_TOTAL / TS;   // 4096
    pink_add_kernel<<<blocks, 256, 0, stream>>>(audio, white, partials, out);
}